// Round 5
// baseline (90.247 us; speedup 1.0000x reference)
//
#include <hip/hip_runtime.h>

#define BB 32
#define SS 22
#define NN 2048
#define HH 8
#define DKK 8
#define PP 6
#define TT 24   // t padded to multiple of 4 (pads have w=0, bias=-1000 -> contribute 0)

__global__ __launch_bounds__(256, 4) void mha_kernel(
    const float* __restrict__ q, const float* __restrict__ k, const float* __restrict__ v,
    const int* __restrict__ mask,
    const float* __restrict__ Wq, const float* __restrict__ bq,
    const float* __restrict__ Wk, const float* __restrict__ bk,
    const float* __restrict__ Wv, const float* __restrict__ bv,
    const float* __restrict__ Wc, const float* __restrict__ bc,
    const float* __restrict__ Wf, const float* __restrict__ bf,
    float* __restrict__ out)
{
    __shared__ float Ms[HH][9];
    __shared__ float Us[HH][3];
    __shared__ unsigned mb[SS];
    __shared__ __align__(16) float biasL[SS][TT];  // 0.f kept, -1000.f masked (exp2 -> exact 0)
    __shared__ float wflL[HH][SS];                 // Wf rows; rows 6,7 zero
    __shared__ float offL[HH];                     // bf[p] + bc0*sum_s Wf[p,s]; 6,7 zero

    const int tid = threadIdx.x;
    // --- per-block precompute of collapsed weight forms ---
    if (tid < 72) {
        int hh = tid / 9, ij = tid - hh * 9, i = ij / 3, j = ij - i * 3;
        float acc = 0.f;
        for (int d = 0; d < DKK; ++d) {
            int c = hh * DKK + d;
            float a  = (i == 0) ? Wq[2 * c] : (i == 1) ? Wq[2 * c + 1] : bq[c];
            float bb = (j == 0) ? Wk[2 * c] : (j == 1) ? Wk[2 * c + 1] : bk[c];
            acc = fmaf(a, bb, acc);
        }
        Ms[hh][ij] = acc * (1.4426950408889634f / 64.f);  // fold 1/DK^2 and log2(e)
    } else if (tid < 96) {
        int r = tid - 72, hh = r / 3, j = r - hh * 3;
        float acc = 0.f;
        for (int d = 0; d < DKK; ++d) {
            int c = hh * DKK + d;
            float a = (j == 0) ? Wv[2 * c] : (j == 1) ? Wv[2 * c + 1] : bv[c];
            acc = fmaf(a, Wc[c], acc);
        }
        Us[hh][j] = acc;
    } else if (tid < 96 + SS) {
        int s = tid - 96;
        unsigned bitsv = 0;
        for (int t = 0; t < SS; ++t)
            if (mask[s * SS + t] != 0) bitsv |= (1u << t);
        mb[s] = bitsv;
    } else if (tid < 96 + SS + HH) {
        int p = tid - (96 + SS);
        float acc = 0.f;
        if (p < PP) {
            float ssum = 0.f;
            for (int t = 0; t < SS; ++t) ssum += Wf[p * SS + t];
            acc = fmaf(bc[0], ssum, bf[p]);
        }
        offL[p] = acc;
    }
    for (int idx = tid; idx < SS * TT; idx += 256) {
        int s = idx / TT, t = idx - s * TT;
        biasL[s][t] = (t < SS && mask[s * SS + t] != 0) ? 0.f : -1000.f;
    }
    for (int idx = tid; idx < HH * SS; idx += 256) {
        int hh = idx / SS, t = idx - hh * SS;
        wflL[hh][t] = (hh < PP) ? Wf[hh * SS + t] : 0.f;
    }
    __syncthreads();

    // lane layout: g = 8 consecutive (b,n) pairs (coalesced), h = head
    const int g    = tid & 7;
    const int h    = (tid >> 3) & 7;
    const int wid  = tid >> 6;
    const int pair = blockIdx.x * 32 + wid * 8 + g;
    const int b    = pair >> 11;            // NN = 2048
    const int n    = pair & (NN - 1);

    const float2* qp = (const float2*)q;
    const float2* kp = (const float2*)k;
    const float2* vp = (const float2*)v;
    const int base = (b * SS) * NN + n;

    const float m00 = Ms[h][0], m01 = Ms[h][1], m02 = Ms[h][2];
    const float m10 = Ms[h][3], m11 = Ms[h][4], m12 = Ms[h][5];
    const float m20 = Ms[h][6], m21 = Ms[h][7], m22 = Ms[h][8];
    const float u0 = Us[h][0], u1 = Us[h][1], u2 = Us[h][2];

    float2 kx[TT];
    float  w[TT];
    float wsA = 0.f, wsB = 0.f;
#pragma unroll
    for (int t = 0; t < SS; ++t) {
        kx[t] = kp[base + t * NN];
        float2 vv = vp[base + t * NN];
        w[t] = fmaf(vv.x, u0, fmaf(vv.y, u1, u2));
        if (t & 1) wsB += w[t]; else wsA += w[t];
    }
    kx[22] = make_float2(0.f, 0.f); kx[23] = make_float2(0.f, 0.f);
    w[22] = 0.f; w[23] = 0.f;
    const float wsum = wsA + wsB;

    float o = offL[h];
#pragma unroll
    for (int s = 0; s < SS; ++s) {
        const unsigned bits = (unsigned)__builtin_amdgcn_readfirstlane((int)mb[s]);
        const float2 qq = qp[base + s * NN];
        float cs;
        if (bits == 0) {
            // fully-masked row: reference softmax degenerates to uniform 1/S
            cs = wsum * (1.f / (float)SS);
        } else {
            const float g0 = fmaf(qq.x, m00, fmaf(qq.y, m10, m20));
            const float g1 = fmaf(qq.x, m01, fmaf(qq.y, m11, m21));
            const float g2 = fmaf(qq.x, m02, fmaf(qq.y, m12, m22));
            float sA = 0.f, sB = 0.f, dA = 0.f, dB = 0.f;
#pragma unroll
            for (int t0 = 0; t0 < TT; t0 += 4) {
                const float4 bb = *(const float4*)&biasL[s][t0];  // broadcast ds_read_b128
                float e0 = __builtin_amdgcn_exp2f(fmaf(g0, kx[t0+0].x, fmaf(g1, kx[t0+0].y, g2)) + bb.x);
                sA += e0; dA = fmaf(e0, w[t0+0], dA);
                float e1 = __builtin_amdgcn_exp2f(fmaf(g0, kx[t0+1].x, fmaf(g1, kx[t0+1].y, g2)) + bb.y);
                sB += e1; dB = fmaf(e1, w[t0+1], dB);
                float e2 = __builtin_amdgcn_exp2f(fmaf(g0, kx[t0+2].x, fmaf(g1, kx[t0+2].y, g2)) + bb.z);
                sA += e2; dA = fmaf(e2, w[t0+2], dA);
                float e3 = __builtin_amdgcn_exp2f(fmaf(g0, kx[t0+3].x, fmaf(g1, kx[t0+3].y, g2)) + bb.w);
                sB += e3; dB = fmaf(e3, w[t0+3], dB);
            }
            cs = (dA + dB) * __builtin_amdgcn_rcpf(sA + sB);
        }
        // merge heads in-loop (masks 8,16,32 flip the h bits of the lane id)
        cs += __shfl_xor(cs, 8);
        cs += __shfl_xor(cs, 16);
        cs += __shfl_xor(cs, 32);
        // epilogue accumulation (rows 6,7 of wflL are zero -> lanes h>=6 stay at 0)
        o = fmaf(cs, wflL[h][s], o);
    }

    if (h < PP)
        out[(b * PP + h) * NN + n] = o;
}

extern "C" void kernel_launch(void* const* d_in, const int* in_sizes, int n_in,
                              void* d_out, int out_size, void* d_ws, size_t ws_size,
                              hipStream_t stream) {
    const float* q  = (const float*)d_in[0];
    const float* k  = (const float*)d_in[1];
    const float* v  = (const float*)d_in[2];
    const int* mask = (const int*)d_in[3];
    const float* Wq = (const float*)d_in[4];
    const float* bq = (const float*)d_in[5];
    const float* Wk = (const float*)d_in[6];
    const float* bk = (const float*)d_in[7];
    const float* Wv = (const float*)d_in[8];
    const float* bv = (const float*)d_in[9];
    const float* Wc = (const float*)d_in[10];
    const float* bc = (const float*)d_in[11];
    const float* Wf = (const float*)d_in[12];
    const float* bf = (const float*)d_in[13];
    float* out = (float*)d_out;

    dim3 grid(BB * NN * HH / 256), block(256);
    hipLaunchKernelGGL(mha_kernel, grid, block, 0, stream,
                       q, k, v, mask, Wq, bq, Wk, bk, Wv, bv, Wc, bc, Wf, bf, out);
}

// Round 6
// 56.618 us; speedup vs baseline: 1.5940x; 1.5940x over previous
//
#include <hip/hip_runtime.h>

#define BB 32
#define SS 22
#define NN 2048
#define HH 8
#define DKK 8
#define PP 6

__global__ __attribute__((amdgpu_flat_work_group_size(256, 256),
                          amdgpu_waves_per_eu(4, 4)))   // pin 4 waves/SIMD -> 128-VGPR budget,
void mha_kernel(                                        // stop the allocator's 8-wave remat heuristic
    const float* __restrict__ q, const float* __restrict__ k, const float* __restrict__ v,
    const int* __restrict__ mask,
    const float* __restrict__ Wq, const float* __restrict__ bq,
    const float* __restrict__ Wk, const float* __restrict__ bk,
    const float* __restrict__ Wv, const float* __restrict__ bv,
    const float* __restrict__ Wc, const float* __restrict__ bc,
    const float* __restrict__ Wf, const float* __restrict__ bf,
    float* __restrict__ out)
{
    __shared__ float Ms[HH][9];
    __shared__ float Us[HH][3];
    __shared__ unsigned mb[SS];

    const int tid = threadIdx.x;
    // --- per-block precompute of the collapsed weight forms ---
    if (tid < 72) {
        int hh = tid / 9, ij = tid - hh * 9, i = ij / 3, j = ij - i * 3;
        float acc = 0.f;
        for (int d = 0; d < DKK; ++d) {
            int c = hh * DKK + d;
            float a  = (i == 0) ? Wq[2 * c] : (i == 1) ? Wq[2 * c + 1] : bq[c];
            float bb = (j == 0) ? Wk[2 * c] : (j == 1) ? Wk[2 * c + 1] : bk[c];
            acc = fmaf(a, bb, acc);
        }
        // fold 1/DK^2 attention scale and log2(e) (for exp2) into M
        Ms[hh][ij] = acc * (1.4426950408889634f / 64.f);
    } else if (tid < 96) {
        int r = tid - 72, hh = r / 3, j = r - hh * 3;
        float acc = 0.f;
        for (int d = 0; d < DKK; ++d) {
            int c = hh * DKK + d;
            float a = (j == 0) ? Wv[2 * c] : (j == 1) ? Wv[2 * c + 1] : bv[c];
            acc = fmaf(a, Wc[c], acc);
        }
        Us[hh][j] = acc;
    } else if (tid < 96 + SS) {
        int s = tid - 96;
        unsigned bitsv = 0;
        for (int t = 0; t < SS; ++t)
            if (mask[s * SS + t] != 0) bitsv |= (1u << t);
        mb[s] = bitsv;
    }
    __syncthreads();

    // Lane layout: g = lane&7 -> 8 consecutive (b,n) (coalesced / broadcast lines);
    // h = (lane>>3)&7 -> head. Head-merge butterfly uses masks 8,16,32.
    const int g    = tid & 7;
    const int h    = (tid >> 3) & 7;
    const int wid  = tid >> 6;                        // wave within block (0..3)
    const int pair = blockIdx.x * 32 + wid * 8 + g;   // 32 pairs per block
    const int b    = pair >> 11;                      // NN = 2048
    const int n    = pair & (NN - 1);

    const float2* qp = (const float2*)q;
    const float2* kp = (const float2*)k;
    const float2* vp = (const float2*)v;
    const int base = (b * SS) * NN + n;   // + s*NN per row

    const float m00 = Ms[h][0], m01 = Ms[h][1], m02 = Ms[h][2];
    const float m10 = Ms[h][3], m11 = Ms[h][4], m12 = Ms[h][5];
    const float m20 = Ms[h][6], m21 = Ms[h][7], m22 = Ms[h][8];
    const float u0 = Us[h][0], u1 = Us[h][1], u2 = Us[h][2];

    // K rows stay resident in VGPRs; V rows are consumed into w on load.
    float2 kx[SS];
    float  w[SS];
    float wsA = 0.f, wsB = 0.f;
#pragma unroll
    for (int t = 0; t < SS; ++t) {
        kx[t] = kp[base + t * NN];
        float2 vv = vp[base + t * NN];
        w[t] = fmaf(vv.x, u0, fmaf(vv.y, u1, u2));
        if (t & 1) wsB += w[t]; else wsA += w[t];
    }
    const float wsum = wsA + wsB;

    float c_part[SS];
#pragma unroll
    for (int s = 0; s < SS; ++s) {
        const unsigned bits = (unsigned)__builtin_amdgcn_readfirstlane((int)mb[s]);
        const float2 qq = qp[base + s * NN];   // streamed, not kept resident
        if (bits == 0) {
            // fully-masked row: reference softmax degenerates to uniform 1/S
            c_part[s] = wsum * (1.f / (float)SS);
        } else {
            const float g0 = fmaf(qq.x, m00, fmaf(qq.y, m10, m20));
            const float g1 = fmaf(qq.x, m01, fmaf(qq.y, m11, m21));
            const float g2 = fmaf(qq.x, m02, fmaf(qq.y, m12, m22));
            float sA = 0.f, sB = 0.f, dA = 0.f, dB = 0.f;
#pragma unroll
            for (int t = 0; t < SS; ++t) {
                if (bits & (1u << t)) {   // wave-uniform branch (bits in SGPR); skips ~half the exps
                    float att = fmaf(g0, kx[t].x, fmaf(g1, kx[t].y, g2));
                    float e = __builtin_amdgcn_exp2f(att);
                    if (t & 1) { sB += e; dB = fmaf(e, w[t], dB); }
                    else       { sA += e; dA = fmaf(e, w[t], dA); }
                }
                // masked entries: exp(-2^15 - m) == 0.0f exactly in the reference
            }
            c_part[s] = (dA + dB) * __builtin_amdgcn_rcpf(sA + sB);
        }
    }

    // merge heads: butterfly sum across the 8 h-lanes (masks 8,16,32)
#pragma unroll
    for (int s = 0; s < SS; ++s) {
        float cv = c_part[s];
        cv += __shfl_xor(cv, 8);
        cv += __shfl_xor(cv, 16);
        cv += __shfl_xor(cv, 32);
        c_part[s] = cv;          // all 8 head-lanes now hold the head-summed value
    }

    // epilogue parallelized over p = h (6 of 8 head-lanes active); writes are
    // 8 consecutive n per head-lane group -> coalesced 32B segments
    if (h < PP) {
        const int p = h;
        const float bc0 = bc[0];
        float o = bf[p];
#pragma unroll
        for (int s = 0; s < SS; ++s)
            o = fmaf(c_part[s] + bc0, Wf[p * SS + s], o);
        out[(b * PP + p) * NN + n] = o;
    }
}

extern "C" void kernel_launch(void* const* d_in, const int* in_sizes, int n_in,
                              void* d_out, int out_size, void* d_ws, size_t ws_size,
                              hipStream_t stream) {
    const float* q  = (const float*)d_in[0];
    const float* k  = (const float*)d_in[1];
    const float* v  = (const float*)d_in[2];
    const int* mask = (const int*)d_in[3];
    const float* Wq = (const float*)d_in[4];
    const float* bq = (const float*)d_in[5];
    const float* Wk = (const float*)d_in[6];
    const float* bk = (const float*)d_in[7];
    const float* Wv = (const float*)d_in[8];
    const float* bv = (const float*)d_in[9];
    const float* Wc = (const float*)d_in[10];
    const float* bc = (const float*)d_in[11];
    const float* Wf = (const float*)d_in[12];
    const float* bf = (const float*)d_in[13];
    float* out = (float*)d_out;

    dim3 grid(BB * NN * HH / 256), block(256);
    hipLaunchKernelGGL(mha_kernel, grid, block, 0, stream,
                       q, k, v, mask, Wq, bq, Wk, bk, Wv, bv, Wc, bc, Wf, bf, out);
}